// Round 1
// baseline (592.883 us; speedup 1.0000x reference)
//
#include <hip/hip_runtime.h>

// GAT layer collapse: softmax over a row-constant score == uniform over neighbors.
// h_prime[i] = (sum_{j: adj[i][j]>0} Wh[j]) / deg(i),  Wh = h @ W.
// a1/a2/LeakyReLU are mathematically irrelevant (softmax shift invariance +
// exp(NEG_BIG) fp32 underflow to 0).

#define N_NODES 10000
#define KPAD    10016          // 10016 = 313*32, padded K for MFMA steps
#define NSTEP   313            // ceil(10000/32)
#define OUTF    64

typedef __attribute__((ext_vector_type(8))) short short8;   // 8 bf16 (4 VGPRs)
typedef __attribute__((ext_vector_type(4))) float f32x4;    // 4 fp32 acc

__device__ __forceinline__ unsigned short f2bf(float x) {
    unsigned int u = __builtin_bit_cast(unsigned int, x);
    u = (u + 0x7FFFu + ((u >> 16) & 1u)) >> 16;   // RNE
    return (unsigned short)u;
}

// Kernel 1: Wh = h @ W (fp32 accumulate), write bf16 packed as
// Bpack[((k>>3)*64 + n)*8 + (k&7)], k-padded with zeros to KPAD rows.
__global__ __launch_bounds__(256) void wh_pack_kernel(
    const float* __restrict__ h, const float* __restrict__ W,
    unsigned short* __restrict__ Bpack) {
    __shared__ float Wl[128 * 64];
    const int tid = threadIdx.x;
    for (int t = tid; t < 128 * 64; t += 256) Wl[t] = W[t];
    __syncthreads();
    const int n  = tid & 63;
    const int rg = tid >> 6;                   // 0..3
    const int i0 = blockIdx.x * 32 + rg * 8;   // grid 313 -> rows 0..10015
    float acc[8] = {0.f,0.f,0.f,0.f,0.f,0.f,0.f,0.f};
    for (int j = 0; j < 128; ++j) {
        const float w = Wl[j * 64 + n];
        #pragma unroll
        for (int t = 0; t < 8; ++t) {
            const int i = i0 + t;
            const float hv = (i < N_NODES) ? h[(size_t)i * 128 + j] : 0.f;
            acc[t] += hv * w;
        }
    }
    #pragma unroll
    for (int t = 0; t < 8; ++t) {
        const int i = i0 + t;
        Bpack[((size_t)(i >> 3) * 64 + n) * 8 + (i & 7)] = f2bf(acc[t]);
    }
}

// Kernel 2: masked aggregation via MFMA. Grid = 625 * S blocks, 256 thr (4 waves).
// Block (tile, q): rows [tile*16, tile*16+16), K-steps s = q*4+wave, stride 4S.
// A-frag from adj on the fly (adj>0 -> bf16 1.0), B-frag from Bpack.
// Deterministic fp32 partials + int deg partials to workspace.
__global__ __launch_bounds__(256) void gat_agg_kernel(
    const int* __restrict__ adj, const unsigned short* __restrict__ Bpack,
    float* __restrict__ Cpart, int* __restrict__ degpart, int S) {
    const int bx   = blockIdx.x;
    const int tile = bx / S;
    const int q    = bx - tile * S;
    const int tidx = threadIdx.x;
    const int wave = tidx >> 6;
    const int lane = tidx & 63;
    const int r16  = lane & 15;
    const int quad = lane >> 4;
    const int row  = tile * 16 + r16;
    const int* __restrict__ arow = adj + (size_t)row * N_NODES;
    const short8* __restrict__ bbase = (const short8*)Bpack;

    f32x4 acc[4];
    #pragma unroll
    for (int c = 0; c < 4; ++c) acc[c] = (f32x4){0.f, 0.f, 0.f, 0.f};
    int msum = 0;

    const int slot = q * 4 + wave;
    const int stride = S * 4;
    for (int s = slot; s < NSTEP; s += stride) {
        const int k0 = s * 32;
        const int kq = k0 + quad * 8;
        short8 afrag;
        if (k0 + 32 <= N_NODES) {
            const int4 v0 = *(const int4*)(arow + kq);
            const int4 v1 = *(const int4*)(arow + kq + 4);
            const int vs[8] = {v0.x, v0.y, v0.z, v0.w, v1.x, v1.y, v1.z, v1.w};
            #pragma unroll
            for (int t = 0; t < 8; ++t) {
                const int m = vs[t] > 0;
                afrag[t] = m ? (short)0x3F80 : (short)0;
                msum += m;
            }
        } else {                                   // tail step (s == 312)
            #pragma unroll
            for (int t = 0; t < 8; ++t) {
                const int k = kq + t;
                const int v = (k < N_NODES) ? arow[k] : 0;
                const int m = v > 0;
                afrag[t] = m ? (short)0x3F80 : (short)0;
                msum += m;
            }
        }
        const int g = (k0 >> 3) + quad;            // k-group index into Bpack
        const short8* __restrict__ bg = bbase + (size_t)g * 64 + r16;
        const short8 b0 = bg[0];
        const short8 b1 = bg[16];
        const short8 b2 = bg[32];
        const short8 b3 = bg[48];
        acc[0] = __builtin_amdgcn_mfma_f32_16x16x32_bf16(afrag, b0, acc[0], 0, 0, 0);
        acc[1] = __builtin_amdgcn_mfma_f32_16x16x32_bf16(afrag, b1, acc[1], 0, 0, 0);
        acc[2] = __builtin_amdgcn_mfma_f32_16x16x32_bf16(afrag, b2, acc[2], 0, 0, 0);
        acc[3] = __builtin_amdgcn_mfma_f32_16x16x32_bf16(afrag, b3, acc[3], 0, 0, 0);
    }

    // deg: fold quads (lanes L, L+16, L+32, L+48 share row r16)
    msum += __shfl_down(msum, 32);
    msum += __shfl_down(msum, 16);

    __shared__ float Cred[4][16][64];
    __shared__ int   degred[4][16];
    #pragma unroll
    for (int c = 0; c < 4; ++c) {
        #pragma unroll
        for (int r = 0; r < 4; ++r)
            Cred[wave][quad * 4 + r][c * 16 + r16] = acc[c][r];
    }
    if (lane < 16) degred[wave][lane] = msum;
    __syncthreads();

    for (int e = tidx; e < 16 * 64; e += 256) {
        const int r = e >> 6, n = e & 63;
        const float sum = Cred[0][r][n] + Cred[1][r][n] + Cred[2][r][n] + Cred[3][r][n];
        Cpart[((size_t)q * N_NODES + tile * 16 + r) * 64 + n] = sum;
    }
    if (tidx < 16)
        degpart[q * N_NODES + tile * 16 + tidx] =
            degred[0][tidx] + degred[1][tidx] + degred[2][tidx] + degred[3][tidx];
}

// Kernel 3: out[i][n] = (sum_q Cpart[q][i][n]) / deg[i]
__global__ __launch_bounds__(256) void finalize_kernel(
    const float* __restrict__ Cpart, const int* __restrict__ degpart,
    float* __restrict__ out, int S) {
    const int idx = blockIdx.x * 256 + threadIdx.x;
    if (idx >= N_NODES * OUTF) return;
    const int i = idx >> 6;
    float sum = 0.f;
    int deg = 0;
    for (int qq = 0; qq < S; ++qq) {
        sum += Cpart[(size_t)qq * N_NODES * OUTF + idx];
        deg += degpart[qq * N_NODES + i];
    }
    out[idx] = (deg > 0) ? sum / (float)deg : 0.f;
}

extern "C" void kernel_launch(void* const* d_in, const int* in_sizes, int n_in,
                              void* d_out, int out_size, void* d_ws, size_t ws_size,
                              hipStream_t stream) {
    const float* h   = (const float*)d_in[0];
    const int*   adj = (const int*)d_in[1];
    const float* W   = (const float*)d_in[2];
    // d_in[3] (a1) and d_in[4] (a2) are mathematically irrelevant (see header).
    float* out = (float*)d_out;
    char*  ws  = (char*)d_ws;

    const size_t bpack_bytes = (size_t)KPAD * OUTF * 2;           // 1.28 MB
    const size_t off = (bpack_bytes + 255) & ~(size_t)255;

    int S = 8;
    while (S > 1) {
        const size_t need = off + (size_t)S * N_NODES * OUTF * 4
                                + (size_t)S * N_NODES * 4;
        if (need <= ws_size) break;
        S >>= 1;
    }

    unsigned short* Bpack = (unsigned short*)ws;
    float* Cpart;
    int*   degpart;
    if (S == 1 && off + (size_t)N_NODES * OUTF * 4 + (size_t)N_NODES * 4 > ws_size) {
        // minimal-workspace fallback: use d_out as the single partial buffer
        Cpart   = out;
        degpart = (int*)(ws + off);
    } else {
        Cpart   = (float*)(ws + off);
        degpart = (int*)(ws + off + (size_t)S * N_NODES * OUTF * 4);
    }

    wh_pack_kernel<<<dim3(313), dim3(256), 0, stream>>>(h, W, Bpack);
    gat_agg_kernel<<<dim3(625 * S), dim3(256), 0, stream>>>(adj, Bpack, Cpart, degpart, S);
    finalize_kernel<<<dim3((N_NODES * OUTF + 255) / 256), dim3(256), 0, stream>>>(
        Cpart, degpart, out, S);
}

// Round 3
// 566.903 us; speedup vs baseline: 1.0458x; 1.0458x over previous
//
#include <hip/hip_runtime.h>

// GAT layer collapse: softmax over a row-constant score == uniform over neighbors.
// h_prime[i] = (sum_{j: adj[i][j]>0} Wh[j]) / deg(i),  Wh = h @ W.
// a1/a2/LeakyReLU are mathematically irrelevant (softmax shift invariance +
// exp(NEG_BIG) fp32 underflow to 0).
//
// R3 = bisect round: gat_agg/finalize/launcher are byte-identical to the
// passing R1; only wh_pack is the new LDS-staged version (+ explicit zeroing
// of Bpack pad rows 10000..10015 to make the pipelines byte-equivalent).

#define N_NODES 10000
#define KPAD    10016          // 10016 = 313*32, padded K for MFMA steps
#define NSTEP   313            // ceil(10000/32)
#define OUTF    64

typedef __attribute__((ext_vector_type(8))) short short8;   // 8 bf16 (4 VGPRs)
typedef __attribute__((ext_vector_type(4))) float f32x4;    // 4 fp32 acc

__device__ __forceinline__ unsigned short f2bf(float x) {
    unsigned int u = __builtin_bit_cast(unsigned int, x);
    u = (u + 0x7FFFu + ((u >> 16) & 1u)) >> 16;   // RNE
    return (unsigned short)u;
}

// Kernel 1 (NEW in R3): Wh = h @ W (fp32), write bf16 packed as
// Bpack[((k>>3)*64 + n)*8 + (k&7)].  Grid 625 blocks x 256 thr; W + 16 h-rows
// staged in LDS via float4 coalesced loads. Block 0 additionally zero-fills
// pad rows 10000..10015 (k-groups 1250,1251) so downstream reads see 0.0,
// exactly as R1's wh_pack produced.
__global__ __launch_bounds__(256) void wh_pack_kernel(
    const float* __restrict__ h, const float* __restrict__ W,
    unsigned short* __restrict__ Bpack) {
    __shared__ float Wl[128 * 64];   // 32 KB
    __shared__ float Hl[16 * 128];   // 8 KB
    const int tid = threadIdx.x;
    const int i0  = blockIdx.x * 16;             // 625 * 16 = 10000 exact
    const float4* W4 = (const float4*)W;
    float4* Wl4 = (float4*)Wl;
    #pragma unroll
    for (int t = 0; t < 8; ++t) Wl4[t * 256 + tid] = W4[t * 256 + tid];
    const float4* H4 = (const float4*)(h + (size_t)i0 * 128);
    float4* Hl4 = (float4*)Hl;
    #pragma unroll
    for (int t = 0; t < 2; ++t) Hl4[t * 256 + tid] = H4[t * 256 + tid];
    if (blockIdx.x == 0) {
        // zero the 1024 pad entries: shorts [640000, 641024)
        #pragma unroll
        for (int t = 0; t < 4; ++t)
            Bpack[(size_t)N_NODES * OUTF + tid * 4 + t] = 0;
    }
    __syncthreads();
    const int n  = tid & 63;
    const int rq = tid >> 6;                     // wave id -> rows rq*4..rq*4+3
    float acc0 = 0.f, acc1 = 0.f, acc2 = 0.f, acc3 = 0.f;
    #pragma unroll 8
    for (int j = 0; j < 128; ++j) {
        const float w = Wl[j * 64 + n];          // stride-1 across lanes
        acc0 += Hl[(rq * 4 + 0) * 128 + j] * w;  // wave-uniform broadcast
        acc1 += Hl[(rq * 4 + 1) * 128 + j] * w;
        acc2 += Hl[(rq * 4 + 2) * 128 + j] * w;
        acc3 += Hl[(rq * 4 + 3) * 128 + j] * w;
    }
    const float accs[4] = {acc0, acc1, acc2, acc3};
    #pragma unroll
    for (int t = 0; t < 4; ++t) {
        const int i = i0 + rq * 4 + t;
        Bpack[((size_t)(i >> 3) * 64 + n) * 8 + (i & 7)] = f2bf(accs[t]);
    }
}

// Kernel 2 (byte-identical to passing R1): masked aggregation via MFMA.
// Grid = 625 * S blocks, 256 thr (4 waves).
// Block (tile, q): rows [tile*16, tile*16+16), K-steps s = q*4+wave, stride 4S.
// A-frag from adj on the fly (adj>0 -> bf16 1.0), B-frag from Bpack.
// Deterministic fp32 partials + int deg partials to workspace.
__global__ __launch_bounds__(256) void gat_agg_kernel(
    const int* __restrict__ adj, const unsigned short* __restrict__ Bpack,
    float* __restrict__ Cpart, int* __restrict__ degpart, int S) {
    const int bx   = blockIdx.x;
    const int tile = bx / S;
    const int q    = bx - tile * S;
    const int tidx = threadIdx.x;
    const int wave = tidx >> 6;
    const int lane = tidx & 63;
    const int r16  = lane & 15;
    const int quad = lane >> 4;
    const int row  = tile * 16 + r16;
    const int* __restrict__ arow = adj + (size_t)row * N_NODES;
    const short8* __restrict__ bbase = (const short8*)Bpack;

    f32x4 acc[4];
    #pragma unroll
    for (int c = 0; c < 4; ++c) acc[c] = (f32x4){0.f, 0.f, 0.f, 0.f};
    int msum = 0;

    const int slot = q * 4 + wave;
    const int stride = S * 4;
    for (int s = slot; s < NSTEP; s += stride) {
        const int k0 = s * 32;
        const int kq = k0 + quad * 8;
        short8 afrag;
        if (k0 + 32 <= N_NODES) {
            const int4 v0 = *(const int4*)(arow + kq);
            const int4 v1 = *(const int4*)(arow + kq + 4);
            const int vs[8] = {v0.x, v0.y, v0.z, v0.w, v1.x, v1.y, v1.z, v1.w};
            #pragma unroll
            for (int t = 0; t < 8; ++t) {
                const int m = vs[t] > 0;
                afrag[t] = m ? (short)0x3F80 : (short)0;
                msum += m;
            }
        } else {                                   // tail step (s == 312)
            #pragma unroll
            for (int t = 0; t < 8; ++t) {
                const int k = kq + t;
                const int v = (k < N_NODES) ? arow[k] : 0;
                const int m = v > 0;
                afrag[t] = m ? (short)0x3F80 : (short)0;
                msum += m;
            }
        }
        const int g = (k0 >> 3) + quad;            // k-group index into Bpack
        const short8* __restrict__ bg = bbase + (size_t)g * 64 + r16;
        const short8 b0 = bg[0];
        const short8 b1 = bg[16];
        const short8 b2 = bg[32];
        const short8 b3 = bg[48];
        acc[0] = __builtin_amdgcn_mfma_f32_16x16x32_bf16(afrag, b0, acc[0], 0, 0, 0);
        acc[1] = __builtin_amdgcn_mfma_f32_16x16x32_bf16(afrag, b1, acc[1], 0, 0, 0);
        acc[2] = __builtin_amdgcn_mfma_f32_16x16x32_bf16(afrag, b2, acc[2], 0, 0, 0);
        acc[3] = __builtin_amdgcn_mfma_f32_16x16x32_bf16(afrag, b3, acc[3], 0, 0, 0);
    }

    // deg: fold quads (lanes L, L+16, L+32, L+48 share row r16)
    msum += __shfl_down(msum, 32);
    msum += __shfl_down(msum, 16);

    __shared__ float Cred[4][16][64];
    __shared__ int   degred[4][16];
    #pragma unroll
    for (int c = 0; c < 4; ++c) {
        #pragma unroll
        for (int r = 0; r < 4; ++r)
            Cred[wave][quad * 4 + r][c * 16 + r16] = acc[c][r];
    }
    if (lane < 16) degred[wave][lane] = msum;
    __syncthreads();

    for (int e = tidx; e < 16 * 64; e += 256) {
        const int r = e >> 6, n = e & 63;
        const float sum = Cred[0][r][n] + Cred[1][r][n] + Cred[2][r][n] + Cred[3][r][n];
        Cpart[((size_t)q * N_NODES + tile * 16 + r) * 64 + n] = sum;
    }
    if (tidx < 16)
        degpart[q * N_NODES + tile * 16 + tidx] =
            degred[0][tidx] + degred[1][tidx] + degred[2][tidx] + degred[3][tidx];
}

// Kernel 3 (byte-identical to passing R1): out[i][n] = (sum_q Cpart[q][i][n]) / deg[i]
__global__ __launch_bounds__(256) void finalize_kernel(
    const float* __restrict__ Cpart, const int* __restrict__ degpart,
    float* __restrict__ out, int S) {
    const int idx = blockIdx.x * 256 + threadIdx.x;
    if (idx >= N_NODES * OUTF) return;
    const int i = idx >> 6;
    float sum = 0.f;
    int deg = 0;
    for (int qq = 0; qq < S; ++qq) {
        sum += Cpart[(size_t)qq * N_NODES * OUTF + idx];
        deg += degpart[qq * N_NODES + i];
    }
    out[idx] = (deg > 0) ? sum / (float)deg : 0.f;
}

extern "C" void kernel_launch(void* const* d_in, const int* in_sizes, int n_in,
                              void* d_out, int out_size, void* d_ws, size_t ws_size,
                              hipStream_t stream) {
    const float* h   = (const float*)d_in[0];
    const int*   adj = (const int*)d_in[1];
    const float* W   = (const float*)d_in[2];
    // d_in[3] (a1) and d_in[4] (a2) are mathematically irrelevant (see header).
    float* out = (float*)d_out;
    char*  ws  = (char*)d_ws;

    const size_t bpack_bytes = (size_t)KPAD * OUTF * 2;           // 1.28 MB
    const size_t off = (bpack_bytes + 255) & ~(size_t)255;

    int S = 8;
    while (S > 1) {
        const size_t need = off + (size_t)S * N_NODES * OUTF * 4
                                + (size_t)S * N_NODES * 4;
        if (need <= ws_size) break;
        S >>= 1;
    }

    unsigned short* Bpack = (unsigned short*)ws;
    float* Cpart;
    int*   degpart;
    if (S == 1 && off + (size_t)N_NODES * OUTF * 4 + (size_t)N_NODES * 4 > ws_size) {
        // minimal-workspace fallback: use d_out as the single partial buffer
        Cpart   = out;
        degpart = (int*)(ws + off);
    } else {
        Cpart   = (float*)(ws + off);
        degpart = (int*)(ws + off + (size_t)S * N_NODES * OUTF * 4);
    }

    wh_pack_kernel<<<dim3(625), dim3(256), 0, stream>>>(h, W, Bpack);
    gat_agg_kernel<<<dim3(625 * S), dim3(256), 0, stream>>>(adj, Bpack, Cpart, degpart, S);
    finalize_kernel<<<dim3((N_NODES * OUTF + 255) / 256), dim3(256), 0, stream>>>(
        Cpart, degpart, out, S);
}